// Round 3
// baseline (953.562 us; speedup 1.0000x reference)
//
#include <hip/hip_runtime.h>
#include <hip/hip_cooperative_groups.h>

namespace cg = cooperative_groups;

#define N_   32
#define C_   512
#define H_   56
#define W_   56
#define S_   16    // NUM_SPLIT
#define CP_  32    // channels per split
#define HW_  (H_*W_)              // 3136
#define PLANES_ (N_*C_)           // 16384
#define GRID_  1024               // co-resident: 4 blocks/CU on 256 CUs
#define PPB_   (PLANES_/GRID_)    // 16 planes per block
#define XPS_   64                 // xp plane stride (floats); 256B -> no cross-block cache-line sharing

typedef float f32x4 __attribute__((ext_vector_type(4)));

__constant__ int d_mx[16] = {0,0,6,0,0,1,1,4,5,1,3,0,0,0,3,2};
__constant__ int d_my[16] = {0,1,0,5,2,0,2,0,0,6,0,4,6,3,5,2};

// Single cooperative kernel:
//  P1: pool 56x56->7x7 (all 1024 blocks, 16 planes each)     -> xp (global, padded)
//  P2: per-(n,split) conv1+conv2+pred+DCT-blend+svec (512 blocks)
//  P3: per-sample MLP hmid (32 blocks)
//  P4: cw-dot + scale (all blocks, same plane map as P1; x is L3-hot from P1)
// Cross-phase visibility: __threadfence() (agent-release, L2 writeback) + grid.sync().
// xp/svec/hmid writes are cache-line exclusive per writer block (padded strides).
__global__ void __launch_bounds__(256, 4) fused_kernel(
        const float* __restrict__ x,
        const float* __restrict__ c1w, const float* __restrict__ c1b,
        const float* __restrict__ c2w, const float* __restrict__ c2b,
        const float* __restrict__ w1,  const float* __restrict__ w2,
        float* __restrict__ out,
        float* __restrict__ xp,       // PLANES_ * XPS_
        float* __restrict__ svec_g,   // N_*C_      (128B-exclusive per (n,s) unit)
        float* __restrict__ hmid_g) { // N_*32      (128B-exclusive per sample)
    __shared__ float tile[HW_];       // 12.25 KB — reused by every phase
    __shared__ float part[196];
    __shared__ float sD[49];
    __shared__ float wcomb[49];
    __shared__ float aux[64];         // a1[0..8], pred state, cw cache
    cg::grid_group grid = cg::this_grid();
    const int bid = blockIdx.x, t = threadIdx.x;

    // ---------------- Phase 1: pool ----------------
    for (int k = 0; k < PPB_; ++k) {
        const int plane = bid + k * GRID_;
        const f32x4* src = reinterpret_cast<const f32x4*>(x + (size_t)plane * HW_);
        f32x4* tl = reinterpret_cast<f32x4*>(tile);
        f32x4 u0 = src[t];
        f32x4 u1 = src[t + 256];
        f32x4 u2 = src[t + 512];
        if (t < 16) tl[t + 768] = src[t + 768];
        tl[t] = u0; tl[t + 256] = u1; tl[t + 512] = u2;
        __syncthreads();
        if (t < 196) {
            int bin = t >> 2, q = t & 3;              // quarter-block = 2 rows x 8 cols
            int oi = bin / 7, oj = bin % 7;
            const float* rp = &tile[(oi * 8 + q * 2) * W_ + oj * 8];
            float s = 0.f;
#pragma unroll
            for (int rr = 0; rr < 2; ++rr)
#pragma unroll
                for (int cc = 0; cc < 8; ++cc) s += rp[rr * W_ + cc];
            part[t] = s;
        }
        __syncthreads();
        if (t < 49) {
            float s = part[t * 4] + part[t * 4 + 1] + part[t * 4 + 2] + part[t * 4 + 3];
            xp[(size_t)plane * XPS_ + t] = s * (1.0f / 64.0f);
        }
        // next iter's tile writes only race with part-readers (different LDS arrays) — safe
    }
    __threadfence();
    grid.sync();

    // ---------------- Phase 2: per-(n,s) head front ----------------
    if (bid < N_ * S_) {
        const int n = bid >> 4, s = bid & 15;
        const float* xs = xp + (size_t)(n * C_ + s * CP_) * XPS_;
        // compact-stage split (stride XPS_ -> stride 49) into LDS
        for (int i = t; i < CP_ * 49; i += 256) {
            int ch = i / 49, p = i - ch * 49;
            tile[i] = xs[ch * XPS_ + p];
        }
        if (t < 49) {
            int f = t / 7, p = t % 7;
            float v = cosf(3.14159265358979323846f * f * (p + 0.5f) / 7.0f) * 0.3779644730092272f;
            if (f >= 1) v *= 1.4142135623730951f;
            sD[t] = v;
        }
        __syncthreads();
        if (t < 9) {                   // conv1: stride-2 3x3 VALID, 9 outputs
            int oi = t / 3, oj = t - oi * 3;
            float acc = c1b[s];
            const float* wb = c1w + s * CP_ * 9;
            for (int ic = 0; ic < CP_; ++ic) {
#pragma unroll
                for (int ki = 0; ki < 3; ++ki)
#pragma unroll
                    for (int kj = 0; kj < 3; ++kj)
                        acc += tile[ic * 49 + (oi * 2 + ki) * 7 + (oj * 2 + kj)]
                             * wb[ic * 9 + ki * 3 + kj];
            }
            aux[t] = fminf(fmaxf(acc + 3.f, 0.f), 6.f) * (1.f / 6.f);
        }
        __syncthreads();
        if (t == 0) {                  // conv2 depthwise + pred decompose
            float acc = c2b[s];
#pragma unroll
            for (int k = 0; k < 9; ++k) acc += aux[k] * c2w[s * 9 + k];
            float pred = fminf(fmaxf(acc * 16.f, 0.f), 14.9f);
            int l = (int)pred;
            aux[16] = (float)l;
            aux[17] = pred - (float)l;
        }
        __syncthreads();
        if (t < 49) {                  // blended DCT filter
            int hh = t / 7, ww = t - hh * 7;
            int l = (int)aux[16], r = l + 1;
            float fr = aux[17];
            wcomb[t] = (1.f - fr) * sD[d_mx[l] * 7 + hh] * sD[d_my[l] * 7 + ww]
                     +        fr  * sD[d_mx[r] * 7 + hh] * sD[d_my[r] * 7 + ww];
        }
        __syncthreads();
        if (t < CP_) {                 // per-channel 49-dot (stride 49 -> conflict-light)
            float acc = 0.f;
#pragma unroll
            for (int p = 0; p < 49; ++p) acc += tile[t * 49 + p] * wcomb[p];
            svec_g[n * C_ + s * CP_ + t] = acc;
        }
    }
    __threadfence();
    grid.sync();

    // ---------------- Phase 3: per-sample MLP (hmid) ----------------
    if (bid < N_) {
        const int n = bid;
        const f32x4* sv_g = reinterpret_cast<const f32x4*>(svec_g + n * C_);
        f32x4* tl = reinterpret_cast<f32x4*>(tile);
        for (int i = t; i < C_ / 4; i += 256) tl[i] = sv_g[i];
        __syncthreads();
        {
            int o = t >> 3, g = t & 7;   // 32 outputs x 8 chunks of 64
            const f32x4* wv = reinterpret_cast<const f32x4*>(w1 + o * C_ + g * 64);
            const f32x4* sv = reinterpret_cast<const f32x4*>(tile + g * 64);
            float acc = 0.f;
#pragma unroll
            for (int j = 0; j < 16; ++j) {
                f32x4 a = sv[j], b = wv[j];
                acc += a.x * b.x + a.y * b.y + a.z * b.z + a.w * b.w;
            }
            tile[512 + t] = acc;         // hpart region
        }
        __syncthreads();
        if (t < 32) {
            float acc = 0.f;
#pragma unroll
            for (int g = 0; g < 8; ++g) acc += tile[512 + t * 8 + g];
            hmid_g[n * 32 + t] = fminf(fmaxf(acc + 3.f, 0.f), 6.f) * (1.f / 6.f);
        }
    }
    __threadfence();
    grid.sync();

    // ---------------- Phase 4: cw + scale (same plane map as P1) ----------------
    if (t < PPB_) {                    // 16 threads: one cw per owned plane
        const int plane = bid + t * GRID_;
        const int n = plane >> 9, c = plane & (C_ - 1);
        const f32x4* hv = reinterpret_cast<const f32x4*>(hmid_g + n * 32);
        const f32x4* wr = reinterpret_cast<const f32x4*>(w2 + c * 32);
        float acc = 0.f;
#pragma unroll
        for (int j = 0; j < 8; ++j) {
            f32x4 h = hv[j], b = wr[j];
            acc += h.x * b.x + h.y * b.y + h.z * b.z + h.w * b.w;
        }
        aux[t] = 1.f / (1.f + expf(-acc));
    }
    __syncthreads();
    for (int k = 0; k < PPB_; ++k) {
        const int plane = bid + k * GRID_;
        const float wsc = aux[k];
        const f32x4* src = reinterpret_cast<const f32x4*>(x + (size_t)plane * HW_);
        f32x4* dst = reinterpret_cast<f32x4*>(out + (size_t)plane * HW_);
        f32x4 u0 = src[t];
        f32x4 u1 = src[t + 256];
        f32x4 u2 = src[t + 512];
        f32x4 u3;
        if (t < 16) u3 = src[t + 768];
        u0 *= wsc; u1 *= wsc; u2 *= wsc;
        __builtin_nontemporal_store(u0, dst + t);
        __builtin_nontemporal_store(u1, dst + t + 256);
        __builtin_nontemporal_store(u2, dst + t + 512);
        if (t < 16) {
            u3 *= wsc;
            __builtin_nontemporal_store(u3, dst + t + 768);
        }
    }
}

extern "C" void kernel_launch(void* const* d_in, const int* in_sizes, int n_in,
                              void* d_out, int out_size, void* d_ws, size_t ws_size,
                              hipStream_t stream) {
    const float* x   = (const float*)d_in[0];
    const float* c1w = (const float*)d_in[1];
    const float* c1b = (const float*)d_in[2];
    const float* c2w = (const float*)d_in[3];
    const float* c2b = (const float*)d_in[4];
    const float* w1  = (const float*)d_in[5];
    const float* w2  = (const float*)d_in[6];
    float* out = (float*)d_out;

    float* xp   = (float*)d_ws;                          // PLANES_*XPS_ fp32 = 4 MB
    float* svec = xp + (size_t)PLANES_ * XPS_;           // N_*C_ fp32
    float* hmid = svec + (size_t)N_ * C_;                // N_*32 fp32

    void* args[] = { (void*)&x, (void*)&c1w, (void*)&c1b, (void*)&c2w, (void*)&c2b,
                     (void*)&w1, (void*)&w2, (void*)&out, (void*)&xp, (void*)&svec,
                     (void*)&hmid };
    hipLaunchCooperativeKernel(reinterpret_cast<void*>(fused_kernel),
                               dim3(GRID_), dim3(256), args, 0, stream);
}

// Round 4
// 430.865 us; speedup vs baseline: 2.2131x; 2.2131x over previous
//
#include <hip/hip_runtime.h>

#define N_   32
#define C_   512
#define H_   56
#define W_   56
#define S_   16    // NUM_SPLIT
#define CP_  32    // channels per split
#define HW_  (H_*W_)              // 3136
#define TOT_ ((size_t)N_*C_*HW_)  // 51380224

typedef float f32x4 __attribute__((ext_vector_type(4)));

__constant__ int d_mx[16] = {0,0,6,0,0,1,1,4,5,1,3,0,0,0,3,2};
__constant__ int d_my[16] = {0,1,0,5,2,0,2,0,0,6,0,4,6,3,5,2};

// ---------------- Kernel 1: adaptive avg pool 56x56 -> 7x7 -------------------
// One plane per 256-thread block (16384 blocks -> deep block-level TLP).
// Fully-coalesced float4 reads staged via LDS; 8x8 block sums. Reads are
// temporal: they warm the 256 MB Infinity Cache so the fused scale kernel's
// x re-read hits L3 instead of HBM.
__global__ void __launch_bounds__(256) pool_kernel(const float* __restrict__ x,
                                                   float* __restrict__ xp) {
    __shared__ float tile[HW_];       // 12.25 KB
    __shared__ float part[49 * 4];
    int plane = blockIdx.x;           // n*C_ + c
    int t = threadIdx.x;
    const float4* src = reinterpret_cast<const float4*>(x + (size_t)plane * HW_);
    for (int i = t; i < HW_ / 4; i += 256)            // 784 float4, coalesced
        *reinterpret_cast<float4*>(&tile[i * 4]) = src[i];
    __syncthreads();
    if (t < 196) {
        int bin = t >> 2, q = t & 3;                  // quarter-block = 2 rows x 8 cols
        int oi = bin / 7, oj = bin % 7;
        const float* rp = &tile[(oi * 8 + q * 2) * W_ + oj * 8];
        float s = 0.f;
#pragma unroll
        for (int rr = 0; rr < 2; ++rr)
#pragma unroll
            for (int cc = 0; cc < 8; ++cc) s += rp[rr * W_ + cc];
        part[t] = s;
    }
    __syncthreads();
    if (t < 49) {
        float s = part[t * 4] + part[t * 4 + 1] + part[t * 4 + 2] + part[t * 4 + 3];
        xp[(size_t)plane * 49 + t] = s * (1.0f / 64.0f);
    }
}

// ---------------- Kernel 2: fused head + scale -------------------------------
// 2048 blocks = 64 blocks per sample, 8 planes per block. Every block
// REDUNDANTLY recomputes its sample's head (conv1 -> conv2 -> pred -> DCT
// blend -> svec -> MLP) from L2-hot xp (~70K FLOP, ~1-2 us, fully parallel
// across blocks — no cross-block sync needed), then computes cw for its own
// 8 channels and does the BW-bound scale of its 8 planes. LDS ~8 KB keeps
// occupancy high for the streaming phase. out stores are nontemporal so they
// don't evict the pool-warmed x from L3.
__global__ void __launch_bounds__(256, 4) hs_kernel(
        const float* __restrict__ x,
        const float* __restrict__ xp,
        const float* __restrict__ c1w, const float* __restrict__ c1b,
        const float* __restrict__ c2w, const float* __restrict__ c2b,
        const float* __restrict__ w1,  const float* __restrict__ w2,
        float* __restrict__ out) {
    __shared__ float sD[49];
    __shared__ float a1[S_ * 9];
    __shared__ float wcomb[S_ * 49];
    __shared__ float svec[C_];
    __shared__ float hpart[256];
    __shared__ float hmid[32];
    __shared__ float cwv[8];
    __shared__ float sfrac[S_];
    __shared__ int   sleft[S_];

    const int bid = blockIdx.x, t = threadIdx.x;
    const int n = bid >> 6;            // sample
    const int r = bid & 63;            // channel-group within sample (8 ch each)
    const float* xpn = xp + (size_t)n * C_ * 49;

    // -------- DCT table (t in [192,241)) and conv1 (t<144) run concurrently --
    if (t >= 192 && t < 241) {
        int u = t - 192, f = u / 7, p = u - f * 7;
        float v = cosf(3.14159265358979323846f * f * (p + 0.5f) / 7.0f) * 0.3779644730092272f;
        if (f >= 1) v *= 1.4142135623730951f;
        sD[u] = v;
    }
    if (t < S_ * 9) {                  // conv1: stride-2 3x3 VALID, 16 splits x 9 out
        int s = t / 9, o = t - s * 9, oi = o / 3, oj = o - oi * 3;
        float acc = c1b[s];
        const float* xb = xpn + s * CP_ * 49;          // L2-hot global
        const float* wb = c1w + s * CP_ * 9;
        for (int ic = 0; ic < CP_; ++ic) {
#pragma unroll
            for (int ki = 0; ki < 3; ++ki)
#pragma unroll
                for (int kj = 0; kj < 3; ++kj)
                    acc += xb[ic * 49 + (oi * 2 + ki) * 7 + (oj * 2 + kj)]
                         * wb[ic * 9 + ki * 3 + kj];
        }
        a1[t] = fminf(fmaxf(acc + 3.f, 0.f), 6.f) * (1.f / 6.f);
    }
    __syncthreads();

    // -------- conv2 (depthwise 3x3 -> 1) + pred decompose --------------------
    if (t < S_) {
        float acc = c2b[t];
#pragma unroll
        for (int k = 0; k < 9; ++k) acc += a1[t * 9 + k] * c2w[t * 9 + k];
        float pred = fminf(fmaxf(acc * 16.f, 0.f), 14.9f);
        int l = (int)pred;
        sleft[t] = l;
        sfrac[t] = pred - (float)l;
    }
    __syncthreads();

    // -------- blended DCT filter per split -----------------------------------
    for (int i = t; i < S_ * 49; i += 256) {
        int s = i / 49, p = i - s * 49, hh = p / 7, ww = p - hh * 7;
        int l = sleft[s], rr = l + 1;
        float fr = sfrac[s];
        wcomb[i] = (1.f - fr) * sD[d_mx[l] * 7 + hh] * sD[d_my[l] * 7 + ww]
                 +        fr  * sD[d_mx[rr] * 7 + hh] * sD[d_my[rr] * 7 + ww];
    }
    __syncthreads();

    // -------- svec: per-channel 49-dot (xp L2-hot, wcomb LDS) ----------------
#pragma unroll
    for (int q = 0; q < 2; ++q) {
        int ch = t + q * 256;
        const float* xb = xpn + ch * 49;
        const float* wb = &wcomb[(ch >> 5) * 49];
        float acc = 0.f;
#pragma unroll
        for (int p = 0; p < 49; ++p) acc += xb[p] * wb[p];
        svec[ch] = acc;
    }
    __syncthreads();

    // -------- hmid = hard_sigmoid(svec @ w1.T) -------------------------------
    {
        int o = t >> 3, g = t & 7;     // 32 outputs x 8 chunks of 64
        const f32x4* wv = reinterpret_cast<const f32x4*>(w1 + o * C_ + g * 64);
        const f32x4* sv = reinterpret_cast<const f32x4*>(&svec[g * 64]);
        float acc = 0.f;
#pragma unroll
        for (int j = 0; j < 16; ++j) {
            f32x4 a = sv[j], b = wv[j];
            acc += a.x * b.x + a.y * b.y + a.z * b.z + a.w * b.w;
        }
        hpart[t] = acc;
    }
    __syncthreads();
    if (t < 32) {
        float acc = 0.f;
#pragma unroll
        for (int g = 0; g < 8; ++g) acc += hpart[t * 8 + g];
        hmid[t] = fminf(fmaxf(acc + 3.f, 0.f), 6.f) * (1.f / 6.f);
    }
    __syncthreads();

    // -------- cw for this block's 8 channels ---------------------------------
    if (t < 8) {
        int c = r * 8 + t;
        const f32x4* hv = reinterpret_cast<const f32x4*>(hmid);
        const f32x4* wr = reinterpret_cast<const f32x4*>(w2 + c * 32);
        float acc = 0.f;
#pragma unroll
        for (int j = 0; j < 8; ++j) {
            f32x4 h = hv[j], b = wr[j];
            acc += h.x * b.x + h.y * b.y + h.z * b.z + h.w * b.w;
        }
        cwv[t] = 1.f / (1.f + expf(-acc));
    }
    __syncthreads();

    // -------- scale this block's 8 planes (x is L3-warm from pool) -----------
#pragma unroll 1
    for (int k = 0; k < 8; ++k) {
        const int plane = n * C_ + r * 8 + k;
        const float wsc = cwv[k];
        const f32x4* src = reinterpret_cast<const f32x4*>(x + (size_t)plane * HW_);
        f32x4* dst = reinterpret_cast<f32x4*>(out + (size_t)plane * HW_);
        f32x4 u0 = src[t];
        f32x4 u1 = src[t + 256];
        f32x4 u2 = src[t + 512];
        f32x4 u3;
        if (t < 16) u3 = src[t + 768];
        u0 *= wsc; u1 *= wsc; u2 *= wsc;
        __builtin_nontemporal_store(u0, dst + t);
        __builtin_nontemporal_store(u1, dst + t + 256);
        __builtin_nontemporal_store(u2, dst + t + 512);
        if (t < 16) {
            u3 *= wsc;
            __builtin_nontemporal_store(u3, dst + t + 768);
        }
    }
}

extern "C" void kernel_launch(void* const* d_in, const int* in_sizes, int n_in,
                              void* d_out, int out_size, void* d_ws, size_t ws_size,
                              hipStream_t stream) {
    const float* x   = (const float*)d_in[0];
    const float* c1w = (const float*)d_in[1];
    const float* c1b = (const float*)d_in[2];
    const float* c2w = (const float*)d_in[3];
    const float* c2b = (const float*)d_in[4];
    const float* w1  = (const float*)d_in[5];
    const float* w2  = (const float*)d_in[6];
    float* out = (float*)d_out;

    float* xp = (float*)d_ws;                    // N*C*49 fp32 = 3.2 MB

    pool_kernel<<<N_ * C_, 256, 0, stream>>>(x, xp);
    hs_kernel<<<N_ * S_ * 4, 256, 0, stream>>>(x, xp, c1w, c1b, c2w, c2b, w1, w2, out);
}

// Round 5
// 393.231 us; speedup vs baseline: 2.4249x; 1.0957x over previous
//
#include <hip/hip_runtime.h>

#define N_   32
#define C_   512
#define H_   56
#define W_   56
#define S_   16    // NUM_SPLIT
#define CP_  32    // channels per split
#define HW_  (H_*W_)              // 3136
#define TOT_ ((size_t)N_*C_*HW_)  // 51380224

typedef float f32x4 __attribute__((ext_vector_type(4)));

__constant__ int d_mx[16] = {0,0,6,0,0,1,1,4,5,1,3,0,0,0,3,2};
__constant__ int d_my[16] = {0,1,0,5,2,0,2,0,0,6,0,4,6,3,5,2};

// ---------------- Kernel 1: adaptive avg pool 56x56 -> 7x7 -------------------
// One plane per 256-thread block (16384 blocks -> deep block TLP, HBM-bound).
// Each float4 (4-aligned col group) lies entirely inside one 8x8 output bin:
// reduce per-thread partials in registers, stage only 784 partials in LDS
// (8x less LDS traffic than staging the full tile). Reads are temporal to
// warm L3 for scale's re-read of x.
__global__ void __launch_bounds__(256) pool_kernel(const float* __restrict__ x,
                                                   float* __restrict__ xp) {
    __shared__ float part[784];       // one partial per float4 position
    int plane = blockIdx.x;           // n*C_ + c
    int t = threadIdx.x;
    const f32x4* src = reinterpret_cast<const f32x4*>(x + (size_t)plane * HW_);
    f32x4 u0 = src[t];
    f32x4 u1 = src[t + 256];
    f32x4 u2 = src[t + 512];
    f32x4 u3;
    if (t < 16) u3 = src[t + 768];
    part[t]       = u0.x + u0.y + u0.z + u0.w;
    part[t + 256] = u1.x + u1.y + u1.z + u1.w;
    part[t + 512] = u2.x + u2.y + u2.z + u2.w;
    if (t < 16) part[t + 768] = u3.x + u3.y + u3.z + u3.w;
    __syncthreads();
    if (t < 49) {
        // bin t: rows rb*8..rb*8+7, col-pairs j = 2*cb, 2*cb+1  (i = row*14 + j)
        int rb = t / 7, cb = t - rb * 7;
        const float* p = &part[rb * 8 * 14 + cb * 2];
        float s = 0.f;
#pragma unroll
        for (int r = 0; r < 8; ++r) s += p[r * 14] + p[r * 14 + 1];
        xp[(size_t)plane * 49 + t] = s * (1.0f / 64.0f);
    }
}

// ---------------- Kernel 2: head (convs + DCT blend + MLP) -> cw -------------
// One 256-thread block per sample, 32 blocks. No bulk LDS staging: xp (3.2 MB
// total, just written by pool) is L2/L3-hot — conv1 and svec read it directly,
// avoiding the serial 98 KB staging preamble on this 12%-of-machine phase.
__global__ void __launch_bounds__(256) head_kernel(
        const float* __restrict__ xp,
        const float* __restrict__ c1w, const float* __restrict__ c1b,
        const float* __restrict__ c2w, const float* __restrict__ c2b,
        const float* __restrict__ w1,  const float* __restrict__ w2,
        float* __restrict__ cwout) {
    __shared__ float sD[49];
    __shared__ float a1[S_ * 9];
    __shared__ float wcomb[S_ * 49];
    __shared__ float svec[C_];
    __shared__ float hpart[256];
    __shared__ float hmid[32];
    __shared__ float sfrac[S_];
    __shared__ int   sleft[S_];

    const int n = blockIdx.x, t = threadIdx.x;
    const float* xpn = xp + (size_t)n * C_ * 49;

    // DCT table (threads 192..240) concurrent with conv1 (threads 0..143)
    if (t >= 192 && t < 241) {
        int u = t - 192, f = u / 7, p = u - f * 7;
        float v = cosf(3.14159265358979323846f * f * (p + 0.5f) / 7.0f) * 0.3779644730092272f;
        if (f >= 1) v *= 1.4142135623730951f;
        sD[u] = v;
    }
    if (t < S_ * 9) {                  // conv1: stride-2 3x3 VALID, 16 splits x 9 out
        int s = t / 9, o = t - s * 9, oi = o / 3, oj = o - oi * 3;
        float acc = c1b[s];
        const float* xb = xpn + s * CP_ * 49;          // L2-hot global
        const float* wb = c1w + s * CP_ * 9;
        for (int ic = 0; ic < CP_; ++ic) {
#pragma unroll
            for (int ki = 0; ki < 3; ++ki)
#pragma unroll
                for (int kj = 0; kj < 3; ++kj)
                    acc += xb[ic * 49 + (oi * 2 + ki) * 7 + (oj * 2 + kj)]
                         * wb[ic * 9 + ki * 3 + kj];
        }
        a1[t] = fminf(fmaxf(acc + 3.f, 0.f), 6.f) * (1.f / 6.f);
    }
    __syncthreads();

    // conv2 (depthwise 3x3 -> 1) + pred decompose
    if (t < S_) {
        float acc = c2b[t];
#pragma unroll
        for (int k = 0; k < 9; ++k) acc += a1[t * 9 + k] * c2w[t * 9 + k];
        float pred = fminf(fmaxf(acc * 16.f, 0.f), 14.9f);
        int l = (int)pred;
        sleft[t] = l;
        sfrac[t] = pred - (float)l;
    }
    __syncthreads();

    // blended DCT filter per split
    for (int i = t; i < S_ * 49; i += 256) {
        int s = i / 49, p = i - s * 49, hh = p / 7, ww = p - hh * 7;
        int l = sleft[s], r = l + 1;
        float fr = sfrac[s];
        wcomb[i] = (1.f - fr) * sD[d_mx[l] * 7 + hh] * sD[d_my[l] * 7 + ww]
                 +        fr  * sD[d_mx[r] * 7 + hh] * sD[d_my[r] * 7 + ww];
    }
    __syncthreads();

    // svec: per-channel 49-dot (xp direct from L2, wcomb in LDS)
#pragma unroll
    for (int q = 0; q < 2; ++q) {
        int ch = t + q * 256;
        const float* xb = xpn + ch * 49;
        const float* wb = &wcomb[(ch >> 5) * 49];
        float acc = 0.f;
#pragma unroll
        for (int p = 0; p < 49; ++p) acc += xb[p] * wb[p];
        svec[ch] = acc;
    }
    __syncthreads();

    // hmid = hard_sigmoid(svec @ w1.T)
    {
        int o = t >> 3, g = t & 7;     // 32 outputs x 8 chunks of 64
        const f32x4* wv = reinterpret_cast<const f32x4*>(w1 + o * C_ + g * 64);
        const f32x4* sv = reinterpret_cast<const f32x4*>(&svec[g * 64]);
        float acc = 0.f;
#pragma unroll
        for (int j = 0; j < 16; ++j) {
            f32x4 a = sv[j], b = wv[j];
            acc += a.x * b.x + a.y * b.y + a.z * b.z + a.w * b.w;
        }
        hpart[t] = acc;
    }
    __syncthreads();
    if (t < 32) {
        float acc = 0.f;
#pragma unroll
        for (int g = 0; g < 8; ++g) acc += hpart[t * 8 + g];
        hmid[t] = fminf(fmaxf(acc + 3.f, 0.f), 6.f) * (1.f / 6.f);
    }
    __syncthreads();

    // cw = sigmoid(hmid @ w2.T)
#pragma unroll
    for (int q = 0; q < 2; ++q) {
        int ch = t + q * 256;
        const f32x4* wr = reinterpret_cast<const f32x4*>(w2 + ch * 32);
        const f32x4* hv = reinterpret_cast<const f32x4*>(hmid);
        float acc = 0.f;
#pragma unroll
        for (int j = 0; j < 8; ++j) {
            f32x4 h = hv[j], b = wr[j];
            acc += h.x * b.x + h.y * b.y + h.z * b.z + h.w * b.w;
        }
        cwout[n * C_ + ch] = 1.f / (1.f + expf(-acc));
    }
}

// ---------------- Kernel 3: out = x * cw[n,c] --------------------------------
// One plane per block: cw is a single uniform scalar load, no division.
// Stores nontemporal (evict-first) so out doesn't flush pool-warmed x from L3;
// x reads temporal to harvest those L3 hits.
__global__ void __launch_bounds__(256) scale_kernel(const float* __restrict__ x,
                                                    const float* __restrict__ cw,
                                                    float* __restrict__ out) {
    int plane = blockIdx.x;
    int t = threadIdx.x;
    float wsc = cw[plane];
    const f32x4* src = reinterpret_cast<const f32x4*>(x + (size_t)plane * HW_);
    f32x4* dst = reinterpret_cast<f32x4*>(out + (size_t)plane * HW_);

    f32x4 u0 = src[t];
    f32x4 u1 = src[t + 256];
    f32x4 u2 = src[t + 512];
    f32x4 u3;
    if (t < 16) u3 = src[t + 768];

    u0 *= wsc;
    u1 *= wsc;
    u2 *= wsc;

    __builtin_nontemporal_store(u0, dst + t);
    __builtin_nontemporal_store(u1, dst + t + 256);
    __builtin_nontemporal_store(u2, dst + t + 512);
    if (t < 16) {
        u3 *= wsc;
        __builtin_nontemporal_store(u3, dst + t + 768);
    }
}

extern "C" void kernel_launch(void* const* d_in, const int* in_sizes, int n_in,
                              void* d_out, int out_size, void* d_ws, size_t ws_size,
                              hipStream_t stream) {
    const float* x   = (const float*)d_in[0];
    const float* c1w = (const float*)d_in[1];
    const float* c1b = (const float*)d_in[2];
    const float* c2w = (const float*)d_in[3];
    const float* c2b = (const float*)d_in[4];
    const float* w1  = (const float*)d_in[5];
    const float* w2  = (const float*)d_in[6];
    float* out = (float*)d_out;

    float* xp    = (float*)d_ws;                 // N*C*49 fp32 = 3.2 MB
    float* cwbuf = xp + (size_t)N_ * C_ * 49;    // N*C fp32

    pool_kernel<<<N_ * C_, 256, 0, stream>>>(x, xp);
    head_kernel<<<N_, 256, 0, stream>>>(xp, c1w, c1b, c2w, c2b, w1, w2, cwbuf);
    scale_kernel<<<N_ * C_, 256, 0, stream>>>(x, cwbuf, out);
}